// Round 11
// baseline (742.397 us; speedup 1.0000x reference)
//
#include <hip/hip_runtime.h>
#include <cstdint>
#include <cstddef>

#define NSAMP 4096
#define KDIM  512
#define TOT   49536   // 3 * (128*128 + 128)
#define NUMN  387     // TOT / 128
#define BK    64
#define LCHUNK 16512  // 128 + 128*128, per-layer temp stride

typedef __attribute__((ext_vector_type(8))) __bf16 bf16x8;
typedef __attribute__((ext_vector_type(4))) __bf16 bf16x4;
typedef __attribute__((ext_vector_type(4))) float  f32x4;
typedef __attribute__((ext_vector_type(16))) float f32x16;

#define AS1 __attribute__((address_space(1)))
#define AS3 __attribute__((address_space(3)))

// ---------------------------------------------------------------------------
// fp32 -> bf16 cast, 4 elements per thread (float4 read, 8B write)
// ---------------------------------------------------------------------------
__global__ void cast_bf16(const float* __restrict__ in, __bf16* __restrict__ out, int n4) {
    int i = blockIdx.x * blockDim.x + threadIdx.x;
    int stride = gridDim.x * blockDim.x;
    for (; i < n4; i += stride) {
        float4 v = ((const float4*)in)[i];
        bf16x4 o = { (__bf16)v.x, (__bf16)v.y, (__bf16)v.z, (__bf16)v.w };
        ((bf16x4*)out)[i] = o;
    }
}

// ---------------------------------------------------------------------------
// Hypernetwork GEMM: C[m][n] = sum_k A[m][k]*B[n][k] + bias[n]
// R15 = R14 (BM=256 x BN=128, 4 waves, single-buffer 48KB, unrolled kt,
// mfma_32x32x16 — best measured: 142us, MfmaUtil 32.5%) + ONE change:
// __launch_bounds__(256, 3). R14's occupancy was 19.4% ~= 1.55 blocks/CU,
// limited by our own launch_bounds(256,2) (min 2 waves/EU -> allocator
// settles at 2 blocks/CU) — NOT by LDS (48KB -> 3 blocks fit in 160KB) or
// VGPR (116 <= 170 for 3 waves/SIMD). A 3rd co-resident block provides one
// more compute phase to cover each stage drain (the ~96us of non-MFMA time).
// Null read pre-registered: dur~140 + occupancy up => LDS port saturated =>
// next structural move is B-direct-to-registers (-33% LDS traffic).
// (Resubmitted unchanged after Round-10 container infra failure.)
// ---------------------------------------------------------------------------
__global__ __launch_bounds__(256, 3) void hyper_gemm(
    const __bf16* __restrict__ A, const __bf16* __restrict__ B,
    const float* __restrict__ bias, __bf16* __restrict__ C)
{
    __shared__ __bf16 As[256 * BK];   // 32 KB
    __shared__ __bf16 Bs[128 * BK];   // 16 KB

    const int tid  = threadIdx.x;
    const int lane = tid & 63;
    const int l31  = lane & 31;       // mfma row/col index
    const int lhi  = lane >> 5;       // 0..1 k-half
    const int lk   = lane & 7;        // xor-swizzle key (= row&7 for reads)
    const int wv   = tid >> 6;        // 0..3
    const int wm   = wv >> 1;         // 0..1 -> 128 output rows each
    const int wn   = wv & 1;          // 0..1 -> 64 output cols each

    // ---- XCD-congruent swizzle: same-n_t blocks -> same XCD, adjacent ids
    const int num_m = gridDim.y;                    // chunk/256
    const int id    = blockIdx.y * NUMN + blockIdx.x;
    const int gsz   = 8 * num_m;                    // supergroup block count
    const int s     = id / gsz;
    const int r     = id % gsz;
    const int base  = s * 8;
    int w = NUMN - base; if (w > 8) w = 8;          // partial last group (387%8=3)
    const int n_t = base + r % w;
    const int m_t = r / w;

    const int m0 = m_t * 256;   // chunk-local row
    const int n0 = n_t * 128;

    f32x16 acc[4][2] = {};      // [mi 32-row][nj 32-col] per-wave 128x64

    // ---- per-thread staging geometry (k-invariant, hoisted; verbatim R13)
    const __bf16* gAp[8];
    const __bf16* gBp[4];
    int ldsAOff[8], ldsBOff[4];
#pragma unroll
    for (int c = 0; c < 8; ++c) {
        int idx  = c * 256 + tid;           // 0..2047
        int row  = idx >> 3;                // 0..255
        int gsrc = (idx & 7) ^ (row & 7);
        gAp[c] = A + (size_t)(m0 + row) * KDIM + gsrc * 8;
        ldsAOff[c] = idx * 8;
    }
#pragma unroll
    for (int c = 0; c < 4; ++c) {
        int idx  = c * 256 + tid;           // 0..1023
        int row  = idx >> 3;                // 0..127
        int gsrc = (idx & 7) ^ (row & 7);
        gBp[c] = B + (size_t)(n0 + row) * KDIM + gsrc * 8;
        ldsBOff[c] = idx * 8;
    }

    // ---- hoisted read bases: for sub-k step ks, lane reads global granule
    // ks*2+lhi -> LDS granule (ks*2+lhi)^lk. 4 bases each for A/B; mi/nj
    // selected by immediate offset (mi*4096B / nj*4096B) in the ds_read.
    const __bf16* aB[4];
    const __bf16* bB[4];
#pragma unroll
    for (int ks = 0; ks < 4; ++ks) {
        int g = (ks * 2 + lhi) ^ lk;
        aB[ks] = As + (wm * 128 + l31) * BK + g * 8;
        bB[ks] = Bs + (wn * 64  + l31) * BK + g * 8;
    }

#pragma unroll
    for (int kt = 0; kt < KDIM / BK; ++kt) {
        // stage tile kt (single buffer; offsets fold to immediates)
#pragma unroll
        for (int c = 0; c < 8; ++c)
            __builtin_amdgcn_global_load_lds((AS1 void*)(gAp[c] + kt * BK),
                (AS3 void*)(As + ldsAOff[c]), 16, 0, 0);
#pragma unroll
        for (int c = 0; c < 4; ++c)
            __builtin_amdgcn_global_load_lds((AS1 void*)(gBp[c] + kt * BK),
                (AS3 void*)(Bs + ldsBOff[c]), 16, 0, 0);
        __syncthreads();

        // 4 sub-k steps x 8 mfma_32x32x16 = full 64-k tile
#pragma unroll
        for (int ks = 0; ks < 4; ++ks) {
            bf16x8 a0 = *(const bf16x8*)(aB[ks] + 0 * 32 * BK);
            bf16x8 a1 = *(const bf16x8*)(aB[ks] + 1 * 32 * BK);
            bf16x8 a2 = *(const bf16x8*)(aB[ks] + 2 * 32 * BK);
            bf16x8 a3 = *(const bf16x8*)(aB[ks] + 3 * 32 * BK);
            bf16x8 b0 = *(const bf16x8*)(bB[ks] + 0 * 32 * BK);
            bf16x8 b1 = *(const bf16x8*)(bB[ks] + 1 * 32 * BK);
            acc[0][0] = __builtin_amdgcn_mfma_f32_32x32x16_bf16(a0, b0, acc[0][0], 0, 0, 0);
            acc[0][1] = __builtin_amdgcn_mfma_f32_32x32x16_bf16(a0, b1, acc[0][1], 0, 0, 0);
            acc[1][0] = __builtin_amdgcn_mfma_f32_32x32x16_bf16(a1, b0, acc[1][0], 0, 0, 0);
            acc[1][1] = __builtin_amdgcn_mfma_f32_32x32x16_bf16(a1, b1, acc[1][1], 0, 0, 0);
            acc[2][0] = __builtin_amdgcn_mfma_f32_32x32x16_bf16(a2, b0, acc[2][0], 0, 0, 0);
            acc[2][1] = __builtin_amdgcn_mfma_f32_32x32x16_bf16(a2, b1, acc[2][1], 0, 0, 0);
            acc[3][0] = __builtin_amdgcn_mfma_f32_32x32x16_bf16(a3, b0, acc[3][0], 0, 0, 0);
            acc[3][1] = __builtin_amdgcn_mfma_f32_32x32x16_bf16(a3, b1, acc[3][1], 0, 0, 0);
        }
        __syncthreads();
    }

    // --- epilogue: 32x32 C/D layout col=lane&31, row=(reg&3)+8*(reg>>2)
    // +4*(lane>>5) [m74/m101-verified]. Lanes 0..31 write 32 consecutive n
    // at one m (64B segment); lanes 32..63 the m+4 row. Fuse bias, cast bf16.
#pragma unroll
    for (int nj = 0; nj < 2; ++nj) {
        int n = n0 + wn * 64 + nj * 32 + l31;
        float bv = bias[n];
#pragma unroll
        for (int mi = 0; mi < 4; ++mi) {
#pragma unroll
            for (int rr = 0; rr < 16; ++rr) {
                int m = m0 + wm * 128 + mi * 32 + (rr & 3) + 8 * (rr >> 2) + 4 * lhi;
                C[(size_t)m * TOT + n] = (__bf16)(acc[mi][nj][rr] + bv);
            }
        }
    }
}

// ---------------------------------------------------------------------------
// Stage 2: per-sample 3-layer MLP with hypernetwork weights from temp chunk.
// Unchanged (T14 cross-layer weight prefetch; bias hoisted). TOT row stride.
// ---------------------------------------------------------------------------
__global__ __launch_bounds__(256) void mlp_kernel(
    const float* __restrict__ x, const __bf16* __restrict__ temp,
    float* __restrict__ out, int samp0)
{
    const int n   = samp0 + blockIdx.x;   // global sample index
    const int tid = threadIdx.x;
    const int wv  = tid >> 6;             // 0..3
    const int l   = tid & 63;
    const int pg  = l >> 4;               // 0..3
    const int qg  = l & 15;               // 0..15

    __shared__ float h[128];
    __shared__ float partial[4][128];

    if (tid < 64) ((float2*)h)[tid] = ((const float2*)(x + (size_t)n * 128))[tid];

    const __bf16* row = temp + (size_t)blockIdx.x * TOT;   // chunk-local temp row

    // prefetch layer-0 weights (independent of h)
    bf16x8 w[8];
#pragma unroll
    for (int i = 0; i < 8; ++i)
        w[i] = *(const bf16x8*)(row + 128 + (size_t)(wv * 32 + i * 4 + pg) * 128 + qg * 8);

    int cum = 0;
#pragma unroll
    for (int layer = 0; layer < 3; ++layer) {
        bf16x8 wn2[8];
        if (layer < 2) {
#pragma unroll
            for (int i = 0; i < 8; ++i)
                wn2[i] = *(const bf16x8*)(row + cum + LCHUNK + 128
                        + (size_t)(wv * 32 + i * 4 + pg) * 128 + qg * 8);
        }
        float bv = 0.f;
        if (tid < 128) bv = (float)row[cum + tid];

        float acc[8] = {0, 0, 0, 0, 0, 0, 0, 0};
        __syncthreads();   // h ready
#pragma unroll
        for (int i = 0; i < 8; ++i) {
            float hp = h[wv * 32 + i * 4 + pg];
#pragma unroll
            for (int j = 0; j < 8; ++j) acc[j] += (float)w[i][j] * hp;
        }
#pragma unroll
        for (int j = 0; j < 8; ++j) {
            acc[j] += __shfl_xor(acc[j], 16);
            acc[j] += __shfl_xor(acc[j], 32);
        }
        if (pg == 0) {
#pragma unroll
            for (int j = 0; j < 8; ++j) partial[wv][qg * 8 + j] = acc[j];
        }
        __syncthreads();   // partials ready; everyone done reading h
        if (tid < 128) {
            float v = partial[0][tid] + partial[1][tid] + partial[2][tid] + partial[3][tid]
                    + bv;
            if (layer < 2) v = fmaxf(v, 0.f);
            h[tid] = v;
        }
        if (layer < 2) {
#pragma unroll
            for (int i = 0; i < 8; ++i) w[i] = wn2[i];
        }
        cum += LCHUNK;
    }
    __syncthreads();
    if (tid < 64) ((float2*)(out + (size_t)n * 128))[tid] = ((const float2*)h)[tid];
}

// ---------------------------------------------------------------------------
extern "C" void kernel_launch(void* const* d_in, const int* in_sizes, int n_in,
                              void* d_out, int out_size, void* d_ws, size_t ws_size,
                              hipStream_t stream) {
    const float* int_x = (const float*)d_in[0];  // 4096 x 512
    const float* x     = (const float*)d_in[1];  // 4096 x 128
    const float* W     = (const float*)d_in[2];  // 49536 x 512
    const float* b     = (const float*)d_in[3];  // 49536
    float* out = (float*)d_out;                  // 4096 x 128

    // workspace layout (bf16): A_bf (4 MB) | W_bf (50.7 MB) | temp chunk
    char* ws = (char*)d_ws;
    __bf16* A_bf = (__bf16*)ws;
    size_t offA = (size_t)NSAMP * KDIM * 2;
    __bf16* W_bf = (__bf16*)(ws + offA);
    size_t offW = offA + (size_t)TOT * KDIM * 2;
    __bf16* temp = (__bf16*)(ws + offW);

    // Adaptive chunk: largest of {4096..256} whose temp fits remaining ws.
    // Deterministic given ws_size -> identical work every call (capture-safe).
    // chunk % 256 == 0 (BM=256).
    size_t remain = (ws_size > offW) ? (ws_size - offW) : 0;
    int chunk = 256;
    for (int c = 4096; c >= 256; c >>= 1) {
        if ((size_t)c * TOT * 2 <= remain) { chunk = c; break; }
    }

    int nA4 = NSAMP * KDIM / 4;
    cast_bf16<<<(nA4 + 255) / 256, 256, 0, stream>>>(int_x, A_bf, nA4);
    int nW4 = TOT * KDIM / 4;
    cast_bf16<<<(nW4 + 255) / 256, 256, 0, stream>>>(W, W_bf, nW4);

    for (int samp0 = 0; samp0 < NSAMP; samp0 += chunk) {
        dim3 grid(NUMN, chunk / 256);   // 387 x (chunk/256)
        hyper_gemm<<<grid, 256, 0, stream>>>(A_bf + (size_t)samp0 * KDIM, W_bf, b, temp);
        mlp_kernel<<<chunk, 256, 0, stream>>>(x, temp, out, samp0);
    }
}

// Round 12
// 499.180 us; speedup vs baseline: 1.4872x; 1.4872x over previous
//
#include <hip/hip_runtime.h>
#include <cstdint>
#include <cstddef>

#define NSAMP 4096
#define KDIM  512
#define TOT   49536   // 3 * (128*128 + 128)
#define NUMN  387     // TOT / 128
#define BK    64
#define LCHUNK 16512  // 128 + 128*128, per-layer temp stride

typedef __attribute__((ext_vector_type(8))) __bf16 bf16x8;
typedef __attribute__((ext_vector_type(4))) __bf16 bf16x4;
typedef __attribute__((ext_vector_type(4))) float  f32x4;
typedef __attribute__((ext_vector_type(16))) float f32x16;

#define AS1 __attribute__((address_space(1)))
#define AS3 __attribute__((address_space(3)))

// ---------------------------------------------------------------------------
// fp32 -> bf16 cast, 4 elements per thread (float4 read, 8B write)
// ---------------------------------------------------------------------------
__global__ void cast_bf16(const float* __restrict__ in, __bf16* __restrict__ out, int n4) {
    int i = blockIdx.x * blockDim.x + threadIdx.x;
    int stride = gridDim.x * blockDim.x;
    for (; i < n4; i += stride) {
        float4 v = ((const float4*)in)[i];
        bf16x4 o = { (__bf16)v.x, (__bf16)v.y, (__bf16)v.z, (__bf16)v.w };
        ((bf16x4*)out)[i] = o;
    }
}

// ---------------------------------------------------------------------------
// Hypernetwork GEMM: C[m][n] = sum_k A[m][k]*B[n][k] + bias[n]
// R16 = R14 GEMM VERBATIM (best measured: 142us/dispatch @ chunk 2048,
// launch_bounds(256,2)). R15's (256,3) spilled the 128-reg accumulator
// (VGPR 116->84, +400MB scratch traffic, 294us) — reverted; 2 waves/SIMD is
// a hard ceiling for this tile's register footprint.
// THE ACTUAL R16 CHANGE IS IN THE HOST: chunk capped at 1024 so that
// W_bf (50.7MB) + temp (101.5MB) = 152MB fits the 256MB L3. Evidence: every
// non-pathological round sustains 1.9-2.25 TB/s hbm_bytes/dur and R14's
// 293MB/2.1TB/s = 140us == measured 142us -> the GEMM is HBM-traffic-bound
// (temp-C write + W fetch), not schedule-bound. L3-resident temp+W removes
// most HBM traffic from dispatches 1..3 entirely.
// ---------------------------------------------------------------------------
__global__ __launch_bounds__(256, 2) void hyper_gemm(
    const __bf16* __restrict__ A, const __bf16* __restrict__ B,
    const float* __restrict__ bias, __bf16* __restrict__ C)
{
    __shared__ __bf16 As[256 * BK];   // 32 KB
    __shared__ __bf16 Bs[128 * BK];   // 16 KB

    const int tid  = threadIdx.x;
    const int lane = tid & 63;
    const int l31  = lane & 31;       // mfma row/col index
    const int lhi  = lane >> 5;       // 0..1 k-half
    const int lk   = lane & 7;        // xor-swizzle key (= row&7 for reads)
    const int wv   = tid >> 6;        // 0..3
    const int wm   = wv >> 1;         // 0..1 -> 128 output rows each
    const int wn   = wv & 1;          // 0..1 -> 64 output cols each

    // ---- XCD-congruent swizzle: same-n_t blocks -> same XCD, adjacent ids
    const int num_m = gridDim.y;                    // chunk/256
    const int id    = blockIdx.y * NUMN + blockIdx.x;
    const int gsz   = 8 * num_m;                    // supergroup block count
    const int s     = id / gsz;
    const int r     = id % gsz;
    const int base  = s * 8;
    int w = NUMN - base; if (w > 8) w = 8;          // partial last group (387%8=3)
    const int n_t = base + r % w;
    const int m_t = r / w;

    const int m0 = m_t * 256;   // chunk-local row
    const int n0 = n_t * 128;

    f32x16 acc[4][2] = {};      // [mi 32-row][nj 32-col] per-wave 128x64

    // ---- per-thread staging geometry (k-invariant, hoisted; verbatim R13)
    const __bf16* gAp[8];
    const __bf16* gBp[4];
    int ldsAOff[8], ldsBOff[4];
#pragma unroll
    for (int c = 0; c < 8; ++c) {
        int idx  = c * 256 + tid;           // 0..2047
        int row  = idx >> 3;                // 0..255
        int gsrc = (idx & 7) ^ (row & 7);
        gAp[c] = A + (size_t)(m0 + row) * KDIM + gsrc * 8;
        ldsAOff[c] = idx * 8;
    }
#pragma unroll
    for (int c = 0; c < 4; ++c) {
        int idx  = c * 256 + tid;           // 0..1023
        int row  = idx >> 3;                // 0..127
        int gsrc = (idx & 7) ^ (row & 7);
        gBp[c] = B + (size_t)(n0 + row) * KDIM + gsrc * 8;
        ldsBOff[c] = idx * 8;
    }

    // ---- hoisted read bases: for sub-k step ks, lane reads global granule
    // ks*2+lhi -> LDS granule (ks*2+lhi)^lk. 4 bases each for A/B; mi/nj
    // selected by immediate offset (mi*4096B / nj*4096B) in the ds_read.
    const __bf16* aB[4];
    const __bf16* bB[4];
#pragma unroll
    for (int ks = 0; ks < 4; ++ks) {
        int g = (ks * 2 + lhi) ^ lk;
        aB[ks] = As + (wm * 128 + l31) * BK + g * 8;
        bB[ks] = Bs + (wn * 64  + l31) * BK + g * 8;
    }

#pragma unroll
    for (int kt = 0; kt < KDIM / BK; ++kt) {
        // stage tile kt (single buffer; offsets fold to immediates)
#pragma unroll
        for (int c = 0; c < 8; ++c)
            __builtin_amdgcn_global_load_lds((AS1 void*)(gAp[c] + kt * BK),
                (AS3 void*)(As + ldsAOff[c]), 16, 0, 0);
#pragma unroll
        for (int c = 0; c < 4; ++c)
            __builtin_amdgcn_global_load_lds((AS1 void*)(gBp[c] + kt * BK),
                (AS3 void*)(Bs + ldsBOff[c]), 16, 0, 0);
        __syncthreads();

        // 4 sub-k steps x 8 mfma_32x32x16 = full 64-k tile
#pragma unroll
        for (int ks = 0; ks < 4; ++ks) {
            bf16x8 a0 = *(const bf16x8*)(aB[ks] + 0 * 32 * BK);
            bf16x8 a1 = *(const bf16x8*)(aB[ks] + 1 * 32 * BK);
            bf16x8 a2 = *(const bf16x8*)(aB[ks] + 2 * 32 * BK);
            bf16x8 a3 = *(const bf16x8*)(aB[ks] + 3 * 32 * BK);
            bf16x8 b0 = *(const bf16x8*)(bB[ks] + 0 * 32 * BK);
            bf16x8 b1 = *(const bf16x8*)(bB[ks] + 1 * 32 * BK);
            acc[0][0] = __builtin_amdgcn_mfma_f32_32x32x16_bf16(a0, b0, acc[0][0], 0, 0, 0);
            acc[0][1] = __builtin_amdgcn_mfma_f32_32x32x16_bf16(a0, b1, acc[0][1], 0, 0, 0);
            acc[1][0] = __builtin_amdgcn_mfma_f32_32x32x16_bf16(a1, b0, acc[1][0], 0, 0, 0);
            acc[1][1] = __builtin_amdgcn_mfma_f32_32x32x16_bf16(a1, b1, acc[1][1], 0, 0, 0);
            acc[2][0] = __builtin_amdgcn_mfma_f32_32x32x16_bf16(a2, b0, acc[2][0], 0, 0, 0);
            acc[2][1] = __builtin_amdgcn_mfma_f32_32x32x16_bf16(a2, b1, acc[2][1], 0, 0, 0);
            acc[3][0] = __builtin_amdgcn_mfma_f32_32x32x16_bf16(a3, b0, acc[3][0], 0, 0, 0);
            acc[3][1] = __builtin_amdgcn_mfma_f32_32x32x16_bf16(a3, b1, acc[3][1], 0, 0, 0);
        }
        __syncthreads();
    }

    // --- epilogue: 32x32 C/D layout col=lane&31, row=(reg&3)+8*(reg>>2)
    // +4*(lane>>5) [m74/m101-verified]. Lanes 0..31 write 32 consecutive n
    // at one m (64B segment); lanes 32..63 the m+4 row. Fuse bias, cast bf16.
#pragma unroll
    for (int nj = 0; nj < 2; ++nj) {
        int n = n0 + wn * 64 + nj * 32 + l31;
        float bv = bias[n];
#pragma unroll
        for (int mi = 0; mi < 4; ++mi) {
#pragma unroll
            for (int rr = 0; rr < 16; ++rr) {
                int m = m0 + wm * 128 + mi * 32 + (rr & 3) + 8 * (rr >> 2) + 4 * lhi;
                C[(size_t)m * TOT + n] = (__bf16)(acc[mi][nj][rr] + bv);
            }
        }
    }
}

// ---------------------------------------------------------------------------
// Stage 2: per-sample 3-layer MLP with hypernetwork weights from temp chunk.
// Unchanged (T14 cross-layer weight prefetch; bias hoisted). TOT row stride.
// ---------------------------------------------------------------------------
__global__ __launch_bounds__(256) void mlp_kernel(
    const float* __restrict__ x, const __bf16* __restrict__ temp,
    float* __restrict__ out, int samp0)
{
    const int n   = samp0 + blockIdx.x;   // global sample index
    const int tid = threadIdx.x;
    const int wv  = tid >> 6;             // 0..3
    const int l   = tid & 63;
    const int pg  = l >> 4;               // 0..3
    const int qg  = l & 15;               // 0..15

    __shared__ float h[128];
    __shared__ float partial[4][128];

    if (tid < 64) ((float2*)h)[tid] = ((const float2*)(x + (size_t)n * 128))[tid];

    const __bf16* row = temp + (size_t)blockIdx.x * TOT;   // chunk-local temp row

    // prefetch layer-0 weights (independent of h)
    bf16x8 w[8];
#pragma unroll
    for (int i = 0; i < 8; ++i)
        w[i] = *(const bf16x8*)(row + 128 + (size_t)(wv * 32 + i * 4 + pg) * 128 + qg * 8);

    int cum = 0;
#pragma unroll
    for (int layer = 0; layer < 3; ++layer) {
        bf16x8 wn2[8];
        if (layer < 2) {
#pragma unroll
            for (int i = 0; i < 8; ++i)
                wn2[i] = *(const bf16x8*)(row + cum + LCHUNK + 128
                        + (size_t)(wv * 32 + i * 4 + pg) * 128 + qg * 8);
        }
        float bv = 0.f;
        if (tid < 128) bv = (float)row[cum + tid];

        float acc[8] = {0, 0, 0, 0, 0, 0, 0, 0};
        __syncthreads();   // h ready
#pragma unroll
        for (int i = 0; i < 8; ++i) {
            float hp = h[wv * 32 + i * 4 + pg];
#pragma unroll
            for (int j = 0; j < 8; ++j) acc[j] += (float)w[i][j] * hp;
        }
#pragma unroll
        for (int j = 0; j < 8; ++j) {
            acc[j] += __shfl_xor(acc[j], 16);
            acc[j] += __shfl_xor(acc[j], 32);
        }
        if (pg == 0) {
#pragma unroll
            for (int j = 0; j < 8; ++j) partial[wv][qg * 8 + j] = acc[j];
        }
        __syncthreads();   // partials ready; everyone done reading h
        if (tid < 128) {
            float v = partial[0][tid] + partial[1][tid] + partial[2][tid] + partial[3][tid]
                    + bv;
            if (layer < 2) v = fmaxf(v, 0.f);
            h[tid] = v;
        }
        if (layer < 2) {
#pragma unroll
            for (int i = 0; i < 8; ++i) w[i] = wn2[i];
        }
        cum += LCHUNK;
    }
    __syncthreads();
    if (tid < 64) ((float2*)(out + (size_t)n * 128))[tid] = ((const float2*)h)[tid];
}

// ---------------------------------------------------------------------------
extern "C" void kernel_launch(void* const* d_in, const int* in_sizes, int n_in,
                              void* d_out, int out_size, void* d_ws, size_t ws_size,
                              hipStream_t stream) {
    const float* int_x = (const float*)d_in[0];  // 4096 x 512
    const float* x     = (const float*)d_in[1];  // 4096 x 128
    const float* W     = (const float*)d_in[2];  // 49536 x 512
    const float* b     = (const float*)d_in[3];  // 49536
    float* out = (float*)d_out;                  // 4096 x 128

    // workspace layout (bf16): A_bf (4 MB) | W_bf (50.7 MB) | temp chunk
    char* ws = (char*)d_ws;
    __bf16* A_bf = (__bf16*)ws;
    size_t offA = (size_t)NSAMP * KDIM * 2;
    __bf16* W_bf = (__bf16*)(ws + offA);
    size_t offW = offA + (size_t)TOT * KDIM * 2;
    __bf16* temp = (__bf16*)(ws + offW);

    // Chunk CAPPED AT 1024 (the R16 change): W_bf 50.7MB + temp 101.5MB =
    // 152MB < 256MB L3 -> temp round-trip and W re-reads stay L3-resident,
    // removing the dominant HBM traffic (every round measured ~2TB/s
    // effective mixed HBM BW; R14's dur == hbm_bytes/2.1TB/s exactly).
    // Deterministic given ws_size (capture-safe); chunk % 256 == 0.
    size_t remain = (ws_size > offW) ? (ws_size - offW) : 0;
    int chunk = 256;
    for (int c = 1024; c >= 256; c >>= 1) {
        if ((size_t)c * TOT * 2 <= remain) { chunk = c; break; }
    }

    int nA4 = NSAMP * KDIM / 4;
    cast_bf16<<<(nA4 + 255) / 256, 256, 0, stream>>>(int_x, A_bf, nA4);
    int nW4 = TOT * KDIM / 4;
    cast_bf16<<<(nW4 + 255) / 256, 256, 0, stream>>>(W, W_bf, nW4);

    for (int samp0 = 0; samp0 < NSAMP; samp0 += chunk) {
        dim3 grid(NUMN, chunk / 256);   // 387 x (chunk/256)
        hyper_gemm<<<grid, 256, 0, stream>>>(A_bf + (size_t)samp0 * KDIM, W_bf, b, temp);
        mlp_kernel<<<chunk, 256, 0, stream>>>(x, temp, out, samp0);
    }
}

// Round 13
// 477.712 us; speedup vs baseline: 1.5541x; 1.0449x over previous
//
#include <hip/hip_runtime.h>
#include <cstdint>
#include <cstddef>

#define NSAMP 4096
#define KDIM  512
#define TOT   49536   // 3 * (128*128 + 128)
#define NUMN  387     // TOT / 128
#define BK    64
#define LCHUNK 16512  // 128 + 128*128, per-layer temp stride

typedef __attribute__((ext_vector_type(8))) __bf16 bf16x8;
typedef __attribute__((ext_vector_type(4))) __bf16 bf16x4;
typedef __attribute__((ext_vector_type(4))) float  f32x4;
typedef __attribute__((ext_vector_type(16))) float f32x16;

#define AS1 __attribute__((address_space(1)))
#define AS3 __attribute__((address_space(3)))

// ---------------------------------------------------------------------------
// fp32 -> bf16 cast, 4 elements per thread (float4 read, 8B write)
// ---------------------------------------------------------------------------
__global__ void cast_bf16(const float* __restrict__ in, __bf16* __restrict__ out, int n4) {
    int i = blockIdx.x * blockDim.x + threadIdx.x;
    int stride = gridDim.x * blockDim.x;
    for (; i < n4; i += stride) {
        float4 v = ((const float4*)in)[i];
        bf16x4 o = { (__bf16)v.x, (__bf16)v.y, (__bf16)v.z, (__bf16)v.w };
        ((bf16x4*)out)[i] = o;
    }
}

// ---------------------------------------------------------------------------
// Hypernetwork GEMM: C[m][n] = sum_k A[m][k]*B[n][k] + bias[n]
// R17 = STRICT RESTORE of the best-measured configuration (R9: 470us total;
// hyper_gemm 142us/dispatch @ chunk 2048). BM=256 x BN=128, 4 waves,
// single-buffer 48KB LDS, fully-unrolled kt, mfma_32x32x16,
// launch_bounds(256,2).
// Model locked by 6 falsification rounds:
//  - register pool = 512 VGPR/SIMD; this kernel needs 244/wave (116 arch +
//    128 acc) -> 2 waves/SIMD HARD max (R15: min-waves 3 spilled acc, +400MB
//    scratch, 2x slower).
//  - LDS port ~60-70us/CU + MFMA 42us/CU, partially overlapped -> 142us.
//  - refuted escapes: 256^2 tile (R11, 1 blk/CU), full-K A panel (R10,
//    1 wave/SIMD), direct-B streams (R12, 9x FETCH), 8-phase (R2, K=512 too
//    short), chunk 1024 L3-residency (R16, writes don't drop & per-work
//    regressed -> HBM-traffic theory falsified).
// ---------------------------------------------------------------------------
__global__ __launch_bounds__(256, 2) void hyper_gemm(
    const __bf16* __restrict__ A, const __bf16* __restrict__ B,
    const float* __restrict__ bias, __bf16* __restrict__ C)
{
    __shared__ __bf16 As[256 * BK];   // 32 KB
    __shared__ __bf16 Bs[128 * BK];   // 16 KB

    const int tid  = threadIdx.x;
    const int lane = tid & 63;
    const int l31  = lane & 31;       // mfma row/col index
    const int lhi  = lane >> 5;       // 0..1 k-half
    const int lk   = lane & 7;        // xor-swizzle key (= row&7 for reads)
    const int wv   = tid >> 6;        // 0..3
    const int wm   = wv >> 1;         // 0..1 -> 128 output rows each
    const int wn   = wv & 1;          // 0..1 -> 64 output cols each

    // ---- XCD-congruent swizzle: same-n_t blocks -> same XCD, adjacent ids
    const int num_m = gridDim.y;                    // chunk/256
    const int id    = blockIdx.y * NUMN + blockIdx.x;
    const int gsz   = 8 * num_m;                    // supergroup block count
    const int s     = id / gsz;
    const int r     = id % gsz;
    const int base  = s * 8;
    int w = NUMN - base; if (w > 8) w = 8;          // partial last group (387%8=3)
    const int n_t = base + r % w;
    const int m_t = r / w;

    const int m0 = m_t * 256;   // chunk-local row
    const int n0 = n_t * 128;

    f32x16 acc[4][2] = {};      // [mi 32-row][nj 32-col] per-wave 128x64

    // ---- per-thread staging geometry (k-invariant, hoisted)
    const __bf16* gAp[8];
    const __bf16* gBp[4];
    int ldsAOff[8], ldsBOff[4];
#pragma unroll
    for (int c = 0; c < 8; ++c) {
        int idx  = c * 256 + tid;           // 0..2047
        int row  = idx >> 3;                // 0..255
        int gsrc = (idx & 7) ^ (row & 7);
        gAp[c] = A + (size_t)(m0 + row) * KDIM + gsrc * 8;
        ldsAOff[c] = idx * 8;
    }
#pragma unroll
    for (int c = 0; c < 4; ++c) {
        int idx  = c * 256 + tid;           // 0..1023
        int row  = idx >> 3;                // 0..127
        int gsrc = (idx & 7) ^ (row & 7);
        gBp[c] = B + (size_t)(n0 + row) * KDIM + gsrc * 8;
        ldsBOff[c] = idx * 8;
    }

    // ---- hoisted read bases: for sub-k step ks, lane reads global granule
    // ks*2+lhi -> LDS granule (ks*2+lhi)^lk. 4 bases each for A/B; mi/nj
    // selected by immediate offset (mi*4096B / nj*4096B) in the ds_read.
    const __bf16* aB[4];
    const __bf16* bB[4];
#pragma unroll
    for (int ks = 0; ks < 4; ++ks) {
        int g = (ks * 2 + lhi) ^ lk;
        aB[ks] = As + (wm * 128 + l31) * BK + g * 8;
        bB[ks] = Bs + (wn * 64  + l31) * BK + g * 8;
    }

#pragma unroll
    for (int kt = 0; kt < KDIM / BK; ++kt) {
        // stage tile kt (single buffer; offsets fold to immediates)
#pragma unroll
        for (int c = 0; c < 8; ++c)
            __builtin_amdgcn_global_load_lds((AS1 void*)(gAp[c] + kt * BK),
                (AS3 void*)(As + ldsAOff[c]), 16, 0, 0);
#pragma unroll
        for (int c = 0; c < 4; ++c)
            __builtin_amdgcn_global_load_lds((AS1 void*)(gBp[c] + kt * BK),
                (AS3 void*)(Bs + ldsBOff[c]), 16, 0, 0);
        __syncthreads();

        // 4 sub-k steps x 8 mfma_32x32x16 = full 64-k tile
#pragma unroll
        for (int ks = 0; ks < 4; ++ks) {
            bf16x8 a0 = *(const bf16x8*)(aB[ks] + 0 * 32 * BK);
            bf16x8 a1 = *(const bf16x8*)(aB[ks] + 1 * 32 * BK);
            bf16x8 a2 = *(const bf16x8*)(aB[ks] + 2 * 32 * BK);
            bf16x8 a3 = *(const bf16x8*)(aB[ks] + 3 * 32 * BK);
            bf16x8 b0 = *(const bf16x8*)(bB[ks] + 0 * 32 * BK);
            bf16x8 b1 = *(const bf16x8*)(bB[ks] + 1 * 32 * BK);
            acc[0][0] = __builtin_amdgcn_mfma_f32_32x32x16_bf16(a0, b0, acc[0][0], 0, 0, 0);
            acc[0][1] = __builtin_amdgcn_mfma_f32_32x32x16_bf16(a0, b1, acc[0][1], 0, 0, 0);
            acc[1][0] = __builtin_amdgcn_mfma_f32_32x32x16_bf16(a1, b0, acc[1][0], 0, 0, 0);
            acc[1][1] = __builtin_amdgcn_mfma_f32_32x32x16_bf16(a1, b1, acc[1][1], 0, 0, 0);
            acc[2][0] = __builtin_amdgcn_mfma_f32_32x32x16_bf16(a2, b0, acc[2][0], 0, 0, 0);
            acc[2][1] = __builtin_amdgcn_mfma_f32_32x32x16_bf16(a2, b1, acc[2][1], 0, 0, 0);
            acc[3][0] = __builtin_amdgcn_mfma_f32_32x32x16_bf16(a3, b0, acc[3][0], 0, 0, 0);
            acc[3][1] = __builtin_amdgcn_mfma_f32_32x32x16_bf16(a3, b1, acc[3][1], 0, 0, 0);
        }
        __syncthreads();
    }

    // --- epilogue: 32x32 C/D layout col=lane&31, row=(reg&3)+8*(reg>>2)
    // +4*(lane>>5) [m74/m101-verified]. Fuse bias, cast bf16.
#pragma unroll
    for (int nj = 0; nj < 2; ++nj) {
        int n = n0 + wn * 64 + nj * 32 + l31;
        float bv = bias[n];
#pragma unroll
        for (int mi = 0; mi < 4; ++mi) {
#pragma unroll
            for (int rr = 0; rr < 16; ++rr) {
                int m = m0 + wm * 128 + mi * 32 + (rr & 3) + 8 * (rr >> 2) + 4 * lhi;
                C[(size_t)m * TOT + n] = (__bf16)(acc[mi][nj][rr] + bv);
            }
        }
    }
}

// ---------------------------------------------------------------------------
// Stage 2: per-sample 3-layer MLP with hypernetwork weights from temp chunk.
// Unchanged (T14 cross-layer weight prefetch; bias hoisted). TOT row stride.
// ---------------------------------------------------------------------------
__global__ __launch_bounds__(256) void mlp_kernel(
    const float* __restrict__ x, const __bf16* __restrict__ temp,
    float* __restrict__ out, int samp0)
{
    const int n   = samp0 + blockIdx.x;   // global sample index
    const int tid = threadIdx.x;
    const int wv  = tid >> 6;             // 0..3
    const int l   = tid & 63;
    const int pg  = l >> 4;               // 0..3
    const int qg  = l & 15;               // 0..15

    __shared__ float h[128];
    __shared__ float partial[4][128];

    if (tid < 64) ((float2*)h)[tid] = ((const float2*)(x + (size_t)n * 128))[tid];

    const __bf16* row = temp + (size_t)blockIdx.x * TOT;   // chunk-local temp row

    // prefetch layer-0 weights (independent of h)
    bf16x8 w[8];
#pragma unroll
    for (int i = 0; i < 8; ++i)
        w[i] = *(const bf16x8*)(row + 128 + (size_t)(wv * 32 + i * 4 + pg) * 128 + qg * 8);

    int cum = 0;
#pragma unroll
    for (int layer = 0; layer < 3; ++layer) {
        bf16x8 wn2[8];
        if (layer < 2) {
#pragma unroll
            for (int i = 0; i < 8; ++i)
                wn2[i] = *(const bf16x8*)(row + cum + LCHUNK + 128
                        + (size_t)(wv * 32 + i * 4 + pg) * 128 + qg * 8);
        }
        float bv = 0.f;
        if (tid < 128) bv = (float)row[cum + tid];

        float acc[8] = {0, 0, 0, 0, 0, 0, 0, 0};
        __syncthreads();   // h ready
#pragma unroll
        for (int i = 0; i < 8; ++i) {
            float hp = h[wv * 32 + i * 4 + pg];
#pragma unroll
            for (int j = 0; j < 8; ++j) acc[j] += (float)w[i][j] * hp;
        }
#pragma unroll
        for (int j = 0; j < 8; ++j) {
            acc[j] += __shfl_xor(acc[j], 16);
            acc[j] += __shfl_xor(acc[j], 32);
        }
        if (pg == 0) {
#pragma unroll
            for (int j = 0; j < 8; ++j) partial[wv][qg * 8 + j] = acc[j];
        }
        __syncthreads();   // partials ready; everyone done reading h
        if (tid < 128) {
            float v = partial[0][tid] + partial[1][tid] + partial[2][tid] + partial[3][tid]
                    + bv;
            if (layer < 2) v = fmaxf(v, 0.f);
            h[tid] = v;
        }
        if (layer < 2) {
#pragma unroll
            for (int i = 0; i < 8; ++i) w[i] = wn2[i];
        }
        cum += LCHUNK;
    }
    __syncthreads();
    if (tid < 64) ((float2*)(out + (size_t)n * 128))[tid] = ((const float2*)h)[tid];
}

// ---------------------------------------------------------------------------
extern "C" void kernel_launch(void* const* d_in, const int* in_sizes, int n_in,
                              void* d_out, int out_size, void* d_ws, size_t ws_size,
                              hipStream_t stream) {
    const float* int_x = (const float*)d_in[0];  // 4096 x 512
    const float* x     = (const float*)d_in[1];  // 4096 x 128
    const float* W     = (const float*)d_in[2];  // 49536 x 512
    const float* b     = (const float*)d_in[3];  // 49536
    float* out = (float*)d_out;                  // 4096 x 128

    // workspace layout (bf16): A_bf (4 MB) | W_bf (50.7 MB) | temp chunk
    char* ws = (char*)d_ws;
    __bf16* A_bf = (__bf16*)ws;
    size_t offA = (size_t)NSAMP * KDIM * 2;
    __bf16* W_bf = (__bf16*)(ws + offA);
    size_t offW = offA + (size_t)TOT * KDIM * 2;
    __bf16* temp = (__bf16*)(ws + offW);

    // Adaptive chunk: largest of {4096..256} whose temp fits remaining ws
    // (R9 best-measured config picks 2048 on this harness's ws_size).
    // Deterministic given ws_size (capture-safe); chunk % 256 == 0.
    size_t remain = (ws_size > offW) ? (ws_size - offW) : 0;
    int chunk = 256;
    for (int c = 4096; c >= 256; c >>= 1) {
        if ((size_t)c * TOT * 2 <= remain) { chunk = c; break; }
    }

    int nA4 = NSAMP * KDIM / 4;
    cast_bf16<<<(nA4 + 255) / 256, 256, 0, stream>>>(int_x, A_bf, nA4);
    int nW4 = TOT * KDIM / 4;
    cast_bf16<<<(nW4 + 255) / 256, 256, 0, stream>>>(W, W_bf, nW4);

    for (int samp0 = 0; samp0 < NSAMP; samp0 += chunk) {
        dim3 grid(NUMN, chunk / 256);   // 387 x (chunk/256)
        hyper_gemm<<<grid, 256, 0, stream>>>(A_bf + (size_t)samp0 * KDIM, W_bf, b, temp);
        mlp_kernel<<<chunk, 256, 0, stream>>>(x, temp, out, samp0);
    }
}